// Round 4
// baseline (183.368 us; speedup 1.0000x reference)
//
#include <hip/hip_runtime.h>

// VQ-VAE forward via bf16 MFMA distance scan.
//   score'(t,c) = dot(x,w) + (0.25 - ||w||^2/2)  > 0 always
//   argmax via packed u32: (bits(score') & ~1023) | code, v_max_u32.
//   dist = xsq + 0.5 - 2*score'_trunc ;  SSE = sum(xsq) + sum(per-token dist part)
//
// R4: pre-swizzled W chunks in ws (linear global <-> linear LDS),
//     global_load_lds(16B) staging (no conflicts, no VGPR roundtrip),
//     TOKB=128 / 4 blocks/CU (16 waves/CU), packed-u32 argmax,
//     global-atomic counts, finalize fused into last block.
//
// ws: [0,4096) u32 counts[1024] | [4096,4104) double sse | [4104,4108) u32 done
//     [8192,12288) float wnh[1024] (= 0.25 - 0.5||w||^2)
//     [16384,16384+131072) uint4 wbf_sw[4][2048]  (swizzled bf16 W)

typedef __bf16          bf16x8   __attribute__((ext_vector_type(8)));
typedef float           f32x4    __attribute__((ext_vector_type(4)));
typedef unsigned short  ushortx8 __attribute__((ext_vector_type(8)));

constexpr int D = 64;
constexpr int K = 1024;
constexpr int CHUNK = 256;   // codes per LDS pass
constexpr int TOKB  = 128;   // tokens per block (32/wave x 4 waves)
constexpr float CSHIFT = 0.25f;  // positivity shift: |dot| <= ||x||*||w|| < 0.1

__device__ __forceinline__ unsigned short f2bf(float f) {
  unsigned u = __builtin_bit_cast(unsigned, f);
  u = (u + 0x7fffu + ((u >> 16) & 1u)) >> 16;  // RNE
  return (unsigned short)u;
}

__global__ __launch_bounds__(256) void vq_init(const float* __restrict__ W,
                                               unsigned* __restrict__ counts,
                                               float* __restrict__ wnh,
                                               double* __restrict__ sse,
                                               unsigned* __restrict__ done,
                                               uint4* __restrict__ wbf) {
  const int c = blockIdx.x * 256 + threadIdx.x;  // 0..1023
  const float4* row = reinterpret_cast<const float4*>(W + c * D);
  const int cc = c >> 8, c8 = c & 255;
  const int ct = c8 >> 4, cnl = c8 & 15;
  float s = 0.f;
#pragma unroll
  for (int p = 0; p < 8; ++p) {  // part p = dims p*8..p*8+7
    float4 v0 = row[2 * p], v1 = row[2 * p + 1];
    s = fmaf(v0.x, v0.x, s); s = fmaf(v0.y, v0.y, s);
    s = fmaf(v0.z, v0.z, s); s = fmaf(v0.w, v0.w, s);
    s = fmaf(v1.x, v1.x, s); s = fmaf(v1.y, v1.y, s);
    s = fmaf(v1.z, v1.z, s); s = fmaf(v1.w, v1.w, s);
    ushortx8 pk;
    pk[0] = f2bf(v0.x); pk[1] = f2bf(v0.y); pk[2] = f2bf(v0.z); pk[3] = f2bf(v0.w);
    pk[4] = f2bf(v1.x); pk[5] = f2bf(v1.y); pk[6] = f2bf(v1.z); pk[7] = f2bf(v1.w);
    // slot layout == exact wave read order in vq_main (linear per lane)
    const int slot = ct * 128 + (p >> 2) * 64 + (p & 3) * 16 + cnl;
    wbf[cc * 2048 + slot] = __builtin_bit_cast(uint4, pk);
  }
  wnh[c] = CSHIFT - 0.5f * s;
  counts[c] = 0u;
  if (c == 0) { *sse = 0.0; *done = 0u; }
}

// 256 threads = 4 waves; 32 tokens/wave (2 A-tiles of 16) -> 128 tokens/block.
__global__ __launch_bounds__(256, 4) void vq_main(const float* __restrict__ x,
                                                  const float* __restrict__ Wf,
                                                  const uint4* __restrict__ wbf,
                                                  const float* __restrict__ wnh,
                                                  unsigned* __restrict__ counts,
                                                  double* __restrict__ sse,
                                                  unsigned* __restrict__ done,
                                                  float* __restrict__ out,
                                                  int nblocks, int n_tokens) {
  __shared__ uint4 s_w[CHUNK * 8];   // 32 KB, linear slots
  __shared__ float s_wnh[CHUNK];     // 1 KB
  __shared__ unsigned s_idx[TOKB];   // 512 B
  __shared__ float s_red[4];
  __shared__ double sdd[4];
  __shared__ int sui[4];
  __shared__ unsigned s_lastf;

  const int tid = threadIdx.x;
  const int wv = tid >> 6, lane = tid & 63;
  const int g = lane >> 4, nl = lane & 15;
  const int tokwg = blockIdx.x * TOKB;

  // A fragments: lane holds A[m=nl][k=g*8+j]; 2 token tiles, 2 k-halves.
  bf16x8 afrag[2][2];
  float xsq = 0.f;
#pragma unroll
  for (int tt = 0; tt < 2; ++tt) {
#pragma unroll
    for (int s = 0; s < 2; ++s) {
      const float* px = x + (size_t)(tokwg + wv * 32 + tt * 16 + nl) * D + s * 32 + g * 8;
      float4 v0 = *reinterpret_cast<const float4*>(px);
      float4 v1 = *reinterpret_cast<const float4*>(px + 4);
      xsq = fmaf(v0.x, v0.x, xsq); xsq = fmaf(v0.y, v0.y, xsq);
      xsq = fmaf(v0.z, v0.z, xsq); xsq = fmaf(v0.w, v0.w, xsq);
      xsq = fmaf(v1.x, v1.x, xsq); xsq = fmaf(v1.y, v1.y, xsq);
      xsq = fmaf(v1.z, v1.z, xsq); xsq = fmaf(v1.w, v1.w, xsq);
      ushortx8 pk;
      pk[0] = f2bf(v0.x); pk[1] = f2bf(v0.y); pk[2] = f2bf(v0.z); pk[3] = f2bf(v0.w);
      pk[4] = f2bf(v1.x); pk[5] = f2bf(v1.y); pk[6] = f2bf(v1.z); pk[7] = f2bf(v1.w);
      afrag[tt][s] = __builtin_bit_cast(bf16x8, pk);
    }
  }

  unsigned bestp[2][4];
#pragma unroll
  for (int tt = 0; tt < 2; ++tt)
#pragma unroll
    for (int j = 0; j < 4; ++j) bestp[tt][j] = 0u;  // score' > 0 => bits > 0

  for (int cb = 0; cb < K; cb += CHUNK) {
    const int cc = cb >> 8;
    __syncthreads();  // previous chunk fully consumed
    // Direct global->LDS DMA: slot order == lane order (conflict-free).
#pragma unroll
    for (int it = 0; it < 8; ++it) {
      const int s = wv * 512 + it * 64 + lane;
      __builtin_amdgcn_global_load_lds(
          (const __attribute__((address_space(1))) unsigned*)(wbf + (size_t)cc * 2048 + s),
          (__attribute__((address_space(3))) unsigned*)(&s_w[wv * 512 + it * 64]),
          16, 0, 0);
    }
    s_wnh[tid] = wnh[cb + tid];
    __syncthreads();  // vmcnt+lgkm drained by barrier semantics

#pragma unroll
    for (int ct = 0; ct < CHUNK / 16; ++ct) {
      const float w0 = s_wnh[ct * 16 + nl];
      bf16x8 b0 = __builtin_bit_cast(bf16x8, s_w[ct * 128 + lane]);       // part g
      bf16x8 b1 = __builtin_bit_cast(bf16x8, s_w[ct * 128 + 64 + lane]);  // part 4+g
      const unsigned code0 = (unsigned)(cb + ct * 16) | (unsigned)nl;
#pragma unroll
      for (int tt = 0; tt < 2; ++tt) {
        f32x4 acc = {w0, w0, w0, w0};  // C init = 0.25 - ||w||^2/2
        acc = __builtin_amdgcn_mfma_f32_16x16x32_bf16(afrag[tt][0], b0, acc, 0, 0, 0);
        acc = __builtin_amdgcn_mfma_f32_16x16x32_bf16(afrag[tt][1], b1, acc, 0, 0, 0);
#pragma unroll
        for (int j = 0; j < 4; ++j) {
          unsigned pb = (__builtin_bit_cast(unsigned, acc[j]) & 0xFFFFFC00u) | code0;
          bestp[tt][j] = max(bestp[tt][j], pb);
        }
      }
    }
  }

  // Cross-lane argmax over 16 cols (same g-group); C/D row = 4*g+j, col = nl.
  float ddist = 0.f;
#pragma unroll
  for (int tt = 0; tt < 2; ++tt) {
#pragma unroll
    for (int j = 0; j < 4; ++j) {
      unsigned p = bestp[tt][j];
#pragma unroll
      for (int off = 1; off < 16; off <<= 1) p = max(p, (unsigned)__shfl_xor((int)p, off, 64));
      if (nl == 0) {
        const unsigned ci = p & 1023u;
        s_idx[wv * 32 + tt * 16 + 4 * g + j] = ci;
        atomicAdd(&counts[ci], 1u);
        const float st = __builtin_bit_cast(float, p & 0xFFFFFC00u);
        ddist += fmaf(-2.0f, st, 0.5f);  // dist - xsq = 0.5 - 2*score'
      }
    }
  }

  // Block-reduce SSE contribution: sum(x^2) + sum(dist part).
  float sv = xsq + ddist;
#pragma unroll
  for (int off = 32; off > 0; off >>= 1) sv += __shfl_down(sv, off, 64);
  if (lane == 0) s_red[wv] = sv;
  __syncthreads();  // also publishes s_idx
  if (tid == 0) atomicAdd(sse, (double)((s_red[0] + s_red[1]) + (s_red[2] + s_red[3])));

  // out = W[idx] (fp32 gather; == x + (q-x) to <=1 ulp).
  const int d4 = tid & 15;
#pragma unroll
  for (int tk = 0; tk < TOKB / 16; ++tk) {
    const int tl = tk * 16 + (tid >> 4);
    const unsigned ci = s_idx[tl];
    float4 q = *reinterpret_cast<const float4*>(Wf + ci * D + d4 * 4);
    *reinterpret_cast<float4*>(out + (size_t)(tokwg + tl) * D + d4 * 4) = q;
  }

  // Last-finishing block computes loss/perplexity/usage (saves a launch).
  if (tid == 0) {
    __threadfence();
    unsigned r = __hip_atomic_fetch_add(done, 1u, __ATOMIC_ACQ_REL, __HIP_MEMORY_SCOPE_AGENT);
    s_lastf = (r == (unsigned)(nblocks - 1)) ? 1u : 0u;
  }
  __syncthreads();
  if (s_lastf) {
    double dsum = 0.0;
    int usum = 0;
    const float inv = 1.0f / (float)n_tokens;
    for (int i = tid; i < K; i += 256) {
      unsigned c = __hip_atomic_load(&counts[i], __ATOMIC_RELAXED, __HIP_MEMORY_SCOPE_AGENT);
      float pr = (float)c * inv;
      dsum += (double)(pr * logf(pr + 1e-10f));
      usum += (c >= 1u) ? 1 : 0;
    }
#pragma unroll
    for (int off = 32; off > 0; off >>= 1) {
      dsum += __shfl_down(dsum, off, 64);
      usum += __shfl_down(usum, off, 64);
    }
    if (lane == 0) { sdd[wv] = dsum; sui[wv] = usum; }
    __syncthreads();
    if (tid == 0) {
      double s2 = (sdd[0] + sdd[1]) + (sdd[2] + sdd[3]);
      int u2 = (sui[0] + sui[1]) + (sui[2] + sui[3]);
      unsigned long long sb =
          __hip_atomic_load((unsigned long long*)sse, __ATOMIC_RELAXED, __HIP_MEMORY_SCOPE_AGENT);
      double svv = __builtin_bit_cast(double, sb);
      double mean = svv / ((double)n_tokens * (double)D);
      float* tail = out + (size_t)n_tokens * D;
      tail[0] = 3.0f * (float)mean;   // q_latent + 2*e_latent
      tail[1] = expf(-(float)s2);     // perplexity
      tail[2] = (float)u2;            // usage
    }
  }
}

extern "C" void kernel_launch(void* const* d_in, const int* in_sizes, int n_in,
                              void* d_out, int out_size, void* d_ws, size_t ws_size,
                              hipStream_t stream) {
  const float* x = (const float*)d_in[0];
  const float* W = (const float*)d_in[1];
  float* out = (float*)d_out;

  unsigned* counts = (unsigned*)d_ws;
  double* sse = (double*)((char*)d_ws + 4096);
  unsigned* done = (unsigned*)((char*)d_ws + 4104);
  float* wnh = (float*)((char*)d_ws + 8192);
  uint4* wbf = (uint4*)((char*)d_ws + 16384);

  const int n_tokens = in_sizes[0] / D;  // 131072
  const int blocks = n_tokens / TOKB;    // 1024

  vq_init<<<K / 256, 256, 0, stream>>>(W, counts, wnh, sse, done, wbf);
  vq_main<<<blocks, 256, 0, stream>>>(x, W, wbf, wnh, counts, sse, done, out,
                                      blocks, n_tokens);
}

// Round 5
// 149.738 us; speedup vs baseline: 1.2246x; 1.2246x over previous
//
#include <hip/hip_runtime.h>

// VQ-VAE forward, barrier-free bf16 MFMA distance scan.
//   score'(t,c) = dot(x,w) + (0.25 - ||w||^2/2)  in [0.15,0.35] > 0
//   argmax via packed u32: (bits(score') & ~1023) | (code^1023), v_max_u32
//   (complemented code => ties resolve to SMALLEST index, like reference argmin)
//   dist = xsq + 0.5 - 2*score'_trunc
//
// R5: no LDS staging / no hot-loop barriers — B-fragments stream from
//     pre-swizzled global W (L1/L2 resident, 2x contiguous 1KB loads per tile),
//     128-thread blocks x 1024 = 8 blocks/CU (16 waves/CU),
//     per-block SSE slots (no atomic contention), relaxed-only cross-block
//     atomics + s_waitcnt (NO release fence -> no buffer_wbl2 storm).
//
// ws: [0,4096) u32 counts[1024] | [4096,8192) f32 bsum[1024] | [8192,8196) u32 done
//     [12288,16384) float wnh[1024] (= 0.25 - 0.5||w||^2)
//     [16384,16384+131072) uint4 wbf_sw[8192]  (swizzled bf16 W, read order)

typedef __bf16          bf16x8   __attribute__((ext_vector_type(8)));
typedef float           f32x4    __attribute__((ext_vector_type(4)));
typedef unsigned short  ushortx8 __attribute__((ext_vector_type(8)));

constexpr int D = 64;
constexpr int K = 1024;
constexpr int TOKB = 128;        // tokens/block = 2 waves x 64
constexpr float CSHIFT = 0.25f;  // positivity shift: |dot| <= ||x||*||w|| < 0.1

__device__ __forceinline__ unsigned short f2bf(float f) {
  unsigned u = __builtin_bit_cast(unsigned, f);
  u = (u + 0x7fffu + ((u >> 16) & 1u)) >> 16;  // RNE
  return (unsigned short)u;
}

__global__ __launch_bounds__(256) void vq_init(const float* __restrict__ W,
                                               unsigned* __restrict__ counts,
                                               float* __restrict__ wnh,
                                               unsigned* __restrict__ done,
                                               uint4* __restrict__ wbf) {
  const int c = blockIdx.x * 256 + threadIdx.x;  // 0..1023
  const float4* row = reinterpret_cast<const float4*>(W + c * D);
  float s = 0.f;
#pragma unroll
  for (int p = 0; p < 8; ++p) {  // part p = dims p*8..p*8+7
    float4 v0 = row[2 * p], v1 = row[2 * p + 1];
    s = fmaf(v0.x, v0.x, s); s = fmaf(v0.y, v0.y, s);
    s = fmaf(v0.z, v0.z, s); s = fmaf(v0.w, v0.w, s);
    s = fmaf(v1.x, v1.x, s); s = fmaf(v1.y, v1.y, s);
    s = fmaf(v1.z, v1.z, s); s = fmaf(v1.w, v1.w, s);
    ushortx8 pk;
    pk[0] = f2bf(v0.x); pk[1] = f2bf(v0.y); pk[2] = f2bf(v0.z); pk[3] = f2bf(v0.w);
    pk[4] = f2bf(v1.x); pk[5] = f2bf(v1.y); pk[6] = f2bf(v1.z); pk[7] = f2bf(v1.w);
    // slot order == exact wave read order in vq_main (tile ct, half, lane)
    const int slot = (c >> 4) * 128 + (p >> 2) * 64 + (p & 3) * 16 + (c & 15);
    wbf[slot] = __builtin_bit_cast(uint4, pk);
  }
  wnh[c] = CSHIFT - 0.5f * s;
  counts[c] = 0u;
  if (c == 0) *done = 0u;
}

// 128 threads = 2 waves; 64 tokens/wave (4 A-tiles of 16) -> 128 tokens/block.
__global__ __launch_bounds__(128, 4) void vq_main(const float* __restrict__ x,
                                                  const float* __restrict__ Wf,
                                                  const uint4* __restrict__ wbf,
                                                  const float* __restrict__ wnh,
                                                  unsigned* __restrict__ counts,
                                                  float* __restrict__ bsum,
                                                  unsigned* __restrict__ done,
                                                  float* __restrict__ out,
                                                  int nblocks, int n_tokens) {
  __shared__ float s_wnh[K];        // 4 KB
  __shared__ unsigned s_idx[TOKB];  // 512 B
  __shared__ float s_red[2];
  __shared__ double sdd[2];
  __shared__ int sui[2];
  __shared__ unsigned s_lastf;

  const int tid = threadIdx.x;
  const int wv = tid >> 6, lane = tid & 63;
  const int g = lane >> 4, nl = lane & 15;
  const int tokwg = blockIdx.x * TOKB;

  for (int i = tid; i < K; i += 128) s_wnh[i] = wnh[i];

  // A fragments: lane holds A[m=nl][k=g*8+j]; 4 token tiles, 2 k-halves.
  bf16x8 afrag[4][2];
  float xsq = 0.f;
#pragma unroll
  for (int tt = 0; tt < 4; ++tt) {
#pragma unroll
    for (int s = 0; s < 2; ++s) {
      const float* px = x + (size_t)(tokwg + wv * 64 + tt * 16 + nl) * D + s * 32 + g * 8;
      float4 v0 = *reinterpret_cast<const float4*>(px);
      float4 v1 = *reinterpret_cast<const float4*>(px + 4);
      xsq = fmaf(v0.x, v0.x, xsq); xsq = fmaf(v0.y, v0.y, xsq);
      xsq = fmaf(v0.z, v0.z, xsq); xsq = fmaf(v0.w, v0.w, xsq);
      xsq = fmaf(v1.x, v1.x, xsq); xsq = fmaf(v1.y, v1.y, xsq);
      xsq = fmaf(v1.z, v1.z, xsq); xsq = fmaf(v1.w, v1.w, xsq);
      ushortx8 pk;
      pk[0] = f2bf(v0.x); pk[1] = f2bf(v0.y); pk[2] = f2bf(v0.z); pk[3] = f2bf(v0.w);
      pk[4] = f2bf(v1.x); pk[5] = f2bf(v1.y); pk[6] = f2bf(v1.z); pk[7] = f2bf(v1.w);
      afrag[tt][s] = __builtin_bit_cast(bf16x8, pk);
    }
  }
  __syncthreads();  // s_wnh ready (only barrier before epilogue)

  unsigned bestp[4][4];
#pragma unroll
  for (int tt = 0; tt < 4; ++tt)
#pragma unroll
    for (int j = 0; j < 4; ++j) bestp[tt][j] = 0u;

  // Barrier-free scan: B streams from L1/L2-resident pre-swizzled W.
#pragma unroll 2
  for (int ct = 0; ct < K / 16; ++ct) {
    const float w0 = s_wnh[ct * 16 + nl];
    bf16x8 b0 = __builtin_bit_cast(bf16x8, wbf[ct * 128 + lane]);       // dims 0..31
    bf16x8 b1 = __builtin_bit_cast(bf16x8, wbf[ct * 128 + 64 + lane]);  // dims 32..63
    const unsigned codec = (unsigned)((ct * 16 + nl) ^ 1023);  // complemented
#pragma unroll
    for (int tt = 0; tt < 4; ++tt) {
      f32x4 acc = {w0, w0, w0, w0};  // C init = 0.25 - ||w||^2/2
      acc = __builtin_amdgcn_mfma_f32_16x16x32_bf16(afrag[tt][0], b0, acc, 0, 0, 0);
      acc = __builtin_amdgcn_mfma_f32_16x16x32_bf16(afrag[tt][1], b1, acc, 0, 0, 0);
#pragma unroll
      for (int j = 0; j < 4; ++j) {
        unsigned pb = (__builtin_bit_cast(unsigned, acc[j]) & 0xFFFFFC00u) | codec;
        bestp[tt][j] = max(bestp[tt][j], pb);
      }
    }
  }

  // Cross-lane argmax over 16 cols (lanes sharing a quad); C/D row=4*g+j, col=nl.
  float ddist = 0.f;
#pragma unroll
  for (int tt = 0; tt < 4; ++tt) {
#pragma unroll
    for (int j = 0; j < 4; ++j) {
      unsigned p = bestp[tt][j];
#pragma unroll
      for (int off = 1; off < 16; off <<= 1)
        p = max(p, (unsigned)__shfl_xor((int)p, off, 64));
      if (nl == 0) {
        const unsigned ci = (p & 1023u) ^ 1023u;
        s_idx[wv * 64 + tt * 16 + 4 * g + j] = ci;
        atomicAdd(&counts[ci], 1u);  // relaxed device-scope
        const float st = __builtin_bit_cast(float, p & 0xFFFFFC00u);
        ddist += fmaf(-2.0f, st, 0.5f);  // dist - xsq = 0.5 - 2*score'
      }
    }
  }

  // Per-wave SSE partials -> per-block slot (no contention, no fences).
  float sv = xsq + ddist;
#pragma unroll
  for (int off = 32; off > 0; off >>= 1) sv += __shfl_down(sv, off, 64);
  if (lane == 0) s_red[wv] = sv;
  __syncthreads();  // drains all count atomics (vmcnt 0) + publishes s_idx/s_red

  if (tid == 0) {
    __hip_atomic_store(&bsum[blockIdx.x], s_red[0] + s_red[1],
                       __ATOMIC_RELAXED, __HIP_MEMORY_SCOPE_AGENT);
    __builtin_amdgcn_s_waitcnt(0);  // bsum store at coherence point before done++
    unsigned r = __hip_atomic_fetch_add(done, 1u, __ATOMIC_RELAXED,
                                        __HIP_MEMORY_SCOPE_AGENT);
    s_lastf = (r == (unsigned)(nblocks - 1)) ? 1u : 0u;
  }

  // out = W[idx] (fp32 gather; == x + (q-x) to <=1 ulp).
  const int d4 = tid & 15;
#pragma unroll
  for (int tk = 0; tk < 16; ++tk) {
    const int tl = tk * 8 + (tid >> 4);
    const unsigned ci = s_idx[tl];
    float4 q = *reinterpret_cast<const float4*>(Wf + ci * D + d4 * 4);
    *reinterpret_cast<float4*>(out + (size_t)(tokwg + tl) * D + d4 * 4) = q;
  }

  __syncthreads();
  if (s_lastf) {  // last-finishing block: loss / perplexity / usage
    double dsum = 0.0, ssum = 0.0;
    int usum = 0;
    const float inv = 1.0f / (float)n_tokens;
    for (int i = tid; i < K; i += 128) {
      unsigned c = __hip_atomic_load(&counts[i], __ATOMIC_RELAXED,
                                     __HIP_MEMORY_SCOPE_AGENT);
      float pr = (float)c * inv;
      dsum += (double)(pr * logf(pr + 1e-10f));
      usum += (c >= 1u) ? 1 : 0;
      ssum += (double)__hip_atomic_load(&bsum[i], __ATOMIC_RELAXED,
                                        __HIP_MEMORY_SCOPE_AGENT);
    }
#pragma unroll
    for (int off = 32; off > 0; off >>= 1) {
      dsum += __shfl_down(dsum, off, 64);
      ssum += __shfl_down(ssum, off, 64);
      usum += __shfl_down(usum, off, 64);
    }
    if (lane == 0) { sdd[wv] = dsum; s_red[wv] = (float)0.f; sui[wv] = usum; }
    if (lane == 0) reinterpret_cast<double*>(sdd)[wv] = dsum;
    __shared__ double sds[2];
    if (lane == 0) sds[wv] = ssum;
    __syncthreads();
    if (tid == 0) {
      double s2 = sdd[0] + sdd[1];
      double st = sds[0] + sds[1];
      int u2 = sui[0] + sui[1];
      double mean = st / ((double)n_tokens * (double)D);
      float* tail = out + (size_t)n_tokens * D;
      tail[0] = 3.0f * (float)mean;  // q_latent + 2*e_latent
      tail[1] = expf(-(float)s2);    // perplexity
      tail[2] = (float)u2;           // usage
    }
  }
}

extern "C" void kernel_launch(void* const* d_in, const int* in_sizes, int n_in,
                              void* d_out, int out_size, void* d_ws, size_t ws_size,
                              hipStream_t stream) {
  const float* x = (const float*)d_in[0];
  const float* W = (const float*)d_in[1];
  float* out = (float*)d_out;

  unsigned* counts = (unsigned*)d_ws;
  float* bsum = (float*)((char*)d_ws + 4096);
  unsigned* done = (unsigned*)((char*)d_ws + 8192);
  float* wnh = (float*)((char*)d_ws + 12288);
  uint4* wbf = (uint4*)((char*)d_ws + 16384);

  const int n_tokens = in_sizes[0] / D;  // 131072
  const int blocks = n_tokens / TOKB;    // 1024

  vq_init<<<K / 256, 256, 0, stream>>>(W, counts, wnh, done, wbf);
  vq_main<<<blocks, 128, 0, stream>>>(x, W, wbf, wnh, counts, bsum, done, out,
                                      blocks, n_tokens);
}